// Round 10
// baseline (279.702 us; speedup 1.0000x reference)
//
#include <hip/hip_runtime.h>
#include <hip/hip_bf16.h>

// Problem constants (fixed by the reference)
#define B_ROWS 16384
#define L_SEQ  32

typedef _Float16 f16;
typedef __attribute__((ext_vector_type(4))) _Float16 f16x4;
typedef __attribute__((ext_vector_type(8))) _Float16 f16x8;
typedef __attribute__((ext_vector_type(4))) float f32x4;
typedef __attribute__((ext_vector_type(4))) unsigned int u32x4;

// ---------- fast device math ----------
__device__ __forceinline__ unsigned pkh(float a, float b) {
    return __builtin_bit_cast(unsigned, __builtin_amdgcn_cvt_pkrtz(a, b));
}
__device__ __forceinline__ float tanh_fast(float x) {
    float e = __expf(2.0f * x);
    float r = __builtin_amdgcn_rcpf(e + 1.0f);
    return fmaf(-2.0f, r, 1.0f);
}
__device__ __forceinline__ float gelu_exact(float x) {
    return 0.5f * x * (1.0f + erff(x * 0.70710678118654752440f));
}
// opaque register pins: no remat/reload of weight fragments
__device__ __forceinline__ void pin2(uint2& v) {
    unsigned x0 = v.x, x1 = v.y;
    asm volatile("" : "+v"(x0), "+v"(x1));
    v = make_uint2(x0, x1);
}
__device__ __forceinline__ void pin4(u32x4& v) {
    unsigned x0 = v[0], x1 = v[1], x2 = v[2], x3 = v[3];
    asm volatile("" : "+v"(x0), "+v"(x1), "+v"(x2), "+v"(x3));
    v = (u32x4){x0, x1, x2, x3};
}

// ---------- Fused kernel: preprocessing + MFMA RK4 ODE + MFMA readout ----------
// 8 rows per wave (B-columns 8..15 duplicate rows 0..7; stores guarded n<8).
// Block = 4 waves = 32 rows; grid = 512 blocks -> 2 blocks/CU -> 2 waves/SIMD.
// Layer1 uses 16x16x16 f16 MFMA (K=9 fits in 16): A/B frags are bare pairs.
// Layer-1 C-frag pair (2kk,2kk+1) IS layer-2's B-frag kk (HW-validated r5-r9).
__global__ __launch_bounds__(256, 2) void fused_kernel(
    const float* __restrict__ Xin, const float* __restrict__ Fin,
    const float* __restrict__ TRv,
    const int*   __restrict__ fa_len,
    const float* __restrict__ Wi,  const float* __restrict__ bi,
    const float* __restrict__ W1g, const float* __restrict__ b1g,
    const float* __restrict__ W2g, const float* __restrict__ b2g,
    const float* __restrict__ Wr1, const float* __restrict__ br1,
    const float* __restrict__ Wr2, const float* __restrict__ br2,
    const float* __restrict__ Wr3, const float* __restrict__ br3,
    float* __restrict__ out)
{
    __shared__ __align__(16) float xm[32 * 132];   // [row][i<33][c<4], 528B row stride
#define XM(r_, i_, c_) xm[(r_) * 132 + (i_) * 4 + (c_)]

    const int tid = threadIdx.x;
    const int g16 = tid >> 4, sub = tid & 15;

    // ---- Phase 1: preprocessing (push_zeros + fill), 2 rows per 16-lane group ----
    float mean_r[2]; int fl_r[2];
#pragma unroll
    for (int r = 0; r < 2; ++r) {
        const int row_l = g16 * 2 + r;
        const int row   = blockIdx.x * 32 + row_l;
        const float* Xr = Xin + row * L_SEQ;
        const float* Fr = Fin + row * L_SEQ;
        float xr0 = Xr[sub], xr1 = Xr[sub + 16];
        float fr0 = Fr[sub], fr1 = Fr[sub + 16];
        fl_r[r] = fa_len[row];
        float s = xr0 + xr1;
        s += __shfl_xor(s, 1, 16);
        s += __shfl_xor(s, 2, 16);
        s += __shfl_xor(s, 4, 16);
        s += __shfl_xor(s, 8, 16);
        mean_r[r] = s / (float)fl_r[r];
        XM(row_l, sub, 0)      = fr0; XM(row_l, sub, 1)      = xr0;
        XM(row_l, sub + 16, 0) = fr1; XM(row_l, sub + 16, 1) = xr1;
    }
    __syncthreads();

    float ff[2][2], xf[2][2];
#pragma unroll
    for (int r = 0; r < 2; ++r) {
        const int row_l = g16 * 2 + r;
        const int fl = fl_r[r];
        const float mean = mean_r[r];
        const int shift = L_SEQ - fl;
        int lsrc  = fl - 1 - shift;
        int lsrcC = lsrc < 0 ? 0 : lsrc;
        float lastX = (lsrc >= 0) ? (XM(row_l, lsrcC, 1) / mean) : 0.0f;
        float lastF = XM(row_l, fl - 1, 0);
#pragma unroll
        for (int u = 0; u < 2; ++u) {
            int p = sub + u * 16;
            int src = p - shift;
            int sc  = src < 0 ? 0 : src;
            float fraw = XM(row_l, sc, 0);
            float xraw = XM(row_l, sc, 1);
            ff[r][u] = (src >= 0) ? fraw : lastF;
            xf[r][u] = (src >= 0) ? (xraw / mean) : lastX;
        }
    }
    __syncthreads();
#pragma unroll
    for (int r = 0; r < 2; ++r) {
        const int row_l = g16 * 2 + r;
#pragma unroll
        for (int u = 0; u < 2; ++u) {
            int p = sub + u * 16;
            XM(row_l, p, 0) = ff[r][u];
            XM(row_l, p, 1) = xf[r][u];
        }
    }
    __syncthreads();
#pragma unroll
    for (int r = 0; r < 2; ++r) {
        const int row_l = g16 * 2 + r;
#pragma unroll
        for (int u = 0; u < 2; ++u) {
            int p = sub + u * 16;
            int qd = (p == 0) ? 1 : p;         // m[0] = x[1]-x[0]
            XM(row_l, p, 2) = XM(row_l, qd, 0) - XM(row_l, qd - 1, 0);
            XM(row_l, p, 3) = XM(row_l, qd, 1) - XM(row_l, qd - 1, 1);
        }
    }
    __syncthreads();

    // ---- MFMA-phase lane mapping ----
    const int wv   = tid >> 6;
    const int lane = tid & 63;
    const int n    = lane & 15;     // MFMA column; A-frag m index
    const int q    = lane >> 4;     // lane quarter
    const int nr   = n & 7;         // row-in-wave (cols 8..15 duplicate 0..7)
    const int rowl = wv * 8 + nr;
    const int rowg = blockIdx.x * 32 + rowl;

    // Layer1 A = W1 (K=16 frag: bare pair). k<8 = W1 row, k=8 = b1 (q==2,e==0).
    uint2 a1[16];
#pragma unroll
    for (int t = 0; t < 16; ++t) {
        const float* wr = W1g + (t * 16 + n) * 8 + (q < 2 ? q * 4 : 0);
        float4 w4 = *(const float4*)wr;
        float b1v = b1g[t * 16 + n];
        unsigned d0 = (q < 2) ? pkh(w4.x, w4.y) : (q == 2 ? pkh(b1v, 0.0f) : 0u);
        unsigned d1 = (q < 2) ? pkh(w4.z, w4.w) : 0u;
        a1[t] = make_uint2(d0, d1);
        pin2(a1[t]);                       // force VGPR residency (no remat)
    }
    // Layer2 A = W2 [16 x 256], 8 K-steps of 16x16x32
    u32x4 a2[8];
#pragma unroll
    for (int kk = 0; kk < 8; ++kk) {
        const float* w2r = W2g + n * 256 + kk * 32 + 4 * q;
        float4 p0 = *(const float4*)(w2r);
        float4 p1 = *(const float4*)(w2r + 16);
        a2[kk] = (u32x4){pkh(p0.x, p0.y), pkh(p0.z, p0.w), pkh(p1.x, p1.y), pkh(p1.z, p1.w)};
        pin4(a2[kk]);                      // force VGPR residency (no remat)
    }
    // b2 seed for one layer2 chain (f32 exact)
    f32x4 c2seed;
#pragma unroll
    for (int r = 0; r < 4; ++r) c2seed[r] = b2g[4 * q + r];

    // z0 distributed: lane holds z[2q], z[2q+1] (f32 master) of row rowl
    float f0 = XM(rowl, 0, 0), X0 = XM(rowl, 0, 1);
    float z0 = fmaf(Wi[(2 * q) * 2], f0, fmaf(Wi[(2 * q) * 2 + 1], X0, bi[2 * q]));
    float z1 = fmaf(Wi[(2 * q + 1) * 2], f0, fmaf(Wi[(2 * q + 1) * 2 + 1], X0, bi[2 * q + 1]));

    // bpermute byte-index: lane (q,n) gathers z-pairs from lanes (q&1)*32+n (+16)
    const int bpi = (((q & 1) << 5) + n) << 2;
    const f32x4 zero4 = {0.f, 0.f, 0.f, 0.f};
    const f16x8 zf16 = {0, 0, 0, 0, 0, 0, 0, 0};

    // B(z) K=16 fragment constructor (also used by readout GEMM1)
    auto make_bz = [&](float zza, float zzb) -> uint2 {
        unsigned myz = pkh(zza, zzb);
        int b0 = __builtin_amdgcn_ds_bpermute(bpi, (int)myz);
        int b1 = __builtin_amdgcn_ds_bpermute(bpi + 64, (int)myz);
        unsigned bz0 = (q < 2) ? (unsigned)b0 : (q == 2 ? 0x3C00u : 0u);
        unsigned bz1 = (q < 2) ? (unsigned)b1 : 0u;
        return make_uint2(bz0, bz1);
    };

    auto FEVAL = [&](float zza, float zzb, float d0c, float d1c, float& ko0, float& ko1) {
        uint2 bzp = make_bz(zza, zzb);
        f16x4 bz = __builtin_bit_cast(f16x4, bzp);

        // layer 1: 16 independent K=16 MFMAs -> h tiles (C-frag, lane-local)
        f32x4 c1[16];
#pragma unroll
        for (int t = 0; t < 16; ++t)
            c1[t] = __builtin_amdgcn_mfma_f32_16x16x16f16(
                __builtin_bit_cast(f16x4, a1[t]), bz, zero4, 0, 0, 0);

        // pack then packed-relu (f16 domain): C-frag pair (2kk,2kk+1) IS B-frag kk
        f16x8 hf[8];
#pragma unroll
        for (int kk = 0; kk < 8; ++kk) {
            u32x4 w = (u32x4){pkh(c1[2 * kk][0],     c1[2 * kk][1]),
                              pkh(c1[2 * kk][2],     c1[2 * kk][3]),
                              pkh(c1[2 * kk + 1][0], c1[2 * kk + 1][1]),
                              pkh(c1[2 * kk + 1][2], c1[2 * kk + 1][3])};
            hf[kk] = __builtin_elementwise_max(__builtin_bit_cast(f16x8, w), zf16);
        }

        // layer 2: two independent 4-MFMA chains (halves serial C-dep latency)
        f32x4 c2a = c2seed, c2b = zero4;
#pragma unroll
        for (int kk = 0; kk < 4; ++kk) {
            c2a = __builtin_amdgcn_mfma_f32_16x16x32_f16(
                __builtin_bit_cast(f16x8, a2[kk]), hf[kk], c2a, 0, 0, 0);
            c2b = __builtin_amdgcn_mfma_f32_16x16x32_f16(
                __builtin_bit_cast(f16x8, a2[kk + 4]), hf[kk + 4], c2b, 0, 0, 0);
        }
        f32x4 G = c2a + c2b;

        // g = tanh(G); lane holds G[4q..4q+3] -> k[2q], k[2q+1]
        float t0 = tanh_fast(G[0]), t1 = tanh_fast(G[1]);
        float t2 = tanh_fast(G[2]), t3 = tanh_fast(G[3]);
        ko0 = fmaf(t0, d0c, t1 * d1c);
        ko1 = fmaf(t2, d0c, t3 * d1c);
    };

    // ---- Phase 2: 31 intervals x 2 substeps of RK4 ----
#pragma unroll 1
    for (int i = 0; i < 31; ++i) {
        float4 P0 = *(const float4*)&XM(rowl, i, 0);
        float4 P1 = *(const float4*)&XM(rowl, i + 1, 0);
        float m0f = P0.z, m0X = P0.w, m1f = P1.z, m1X = P1.w;
        float df  = P0.x - P1.x, dXx = P0.y - P1.y;

        float d25f = fmaf(-1.125f, df,  fmaf(0.1875f, m0f, -0.3125f * m1f));
        float d25X = fmaf(-1.125f, dXx, fmaf(0.1875f, m0X, -0.3125f * m1X));
        float d50f = fmaf(-1.5f,   df,  fmaf(-0.25f,  m0f, -0.25f   * m1f));
        float d50X = fmaf(-1.5f,   dXx, fmaf(-0.25f,  m0X, -0.25f   * m1X));
        float d75f = fmaf(-1.125f, df,  fmaf(-0.3125f, m0f, 0.1875f * m1f));
        float d75X = fmaf(-1.125f, dXx, fmaf(-0.3125f, m0X, 0.1875f * m1X));

#pragma unroll 1
        for (int ssi = 0; ssi < 2; ++ssi) {
            float daf = ssi ? d50f : m0f,  daX = ssi ? d50X : m0X;
            float dbf = ssi ? d75f : d25f, dbX = ssi ? d75X : d25X;
            float ddf = ssi ? m1f  : d50f, ddX = ssi ? m1X  : d50X;

            float k1a, k1b, k2a, k2b, k3a, k3b, k4a, k4b, zza, zzb;
            FEVAL(z0, z1, daf, daX, k1a, k1b);
            zza = fmaf(0.25f, k1a, z0); zzb = fmaf(0.25f, k1b, z1);
            FEVAL(zza, zzb, dbf, dbX, k2a, k2b);
            zza = fmaf(0.25f, k2a, z0); zzb = fmaf(0.25f, k2b, z1);
            FEVAL(zza, zzb, dbf, dbX, k3a, k3b);
            zza = fmaf(0.5f, k3a, z0);  zzb = fmaf(0.5f, k3b, z1);
            FEVAL(zza, zzb, ddf, ddX, k4a, k4b);

            float ka = fmaf(2.f, k2a, k1a); ka = fmaf(2.f, k3a, ka);
            float kb = fmaf(2.f, k2b, k1b); kb = fmaf(2.f, k3b, kb);
            z0 = fmaf(1.f / 12.f, ka + k4a, z0);
            z1 = fmaf(1.f / 12.f, kb + k4b, z1);
        }
    }

    // ---- Phase 3: readout (in-register; z already distributed correctly) ----
    // GEMM1: h1 pre-activation, 13 M-tiles over Wr1 (K=16 frags, M=208 pad)
    uint2 bzp = make_bz(z0, z1);
    f16x4 bzr = __builtin_bit_cast(f16x4, bzp);
    f32x4 c1r[13];
#pragma unroll
    for (int t = 0; t < 13; ++t) {
        int m = 16 * t + n;
        uint2 afp = make_uint2(0u, 0u);
        if (q < 2) {
            if (m < 200) {
                float4 w4 = *(const float4*)(Wr1 + m * 8 + 4 * q);
                afp = make_uint2(pkh(w4.x, w4.y), pkh(w4.z, w4.w));
            }
        } else if (q == 2) {
            float b = (m < 200) ? br1[m] : 0.0f;
            afp.x = pkh(b, 0.0f);
        }
        c1r[t] = __builtin_amdgcn_mfma_f32_16x16x16f16(
            __builtin_bit_cast(f16x4, afp), bzr, zero4, 0, 0, 0);
    }

    // gelu + pack into B-frags for GEMM2 (C->B identity)
    f16x8 hf2[7];
#pragma unroll
    for (int kk = 0; kk < 7; ++kk) {
        float g0 = gelu_exact(c1r[2 * kk][0]), g1 = gelu_exact(c1r[2 * kk][1]);
        float g2 = gelu_exact(c1r[2 * kk][2]), g3 = gelu_exact(c1r[2 * kk][3]);
        float g4 = 0.f, g5 = 0.f, g6 = 0.f, g7 = 0.f;
        if (kk < 6) {
            g4 = gelu_exact(c1r[2 * kk + 1][0]); g5 = gelu_exact(c1r[2 * kk + 1][1]);
            g6 = gelu_exact(c1r[2 * kk + 1][2]); g7 = gelu_exact(c1r[2 * kk + 1][3]);
        }
        u32x4 w = (u32x4){pkh(g0, g1), pkh(g2, g3), pkh(g4, g5), pkh(g6, g7)};
        hf2[kk] = __builtin_bit_cast(f16x8, w);
    }

    // GEMM2 from global Wr2 (L2-resident) + gelu + Wr3 dot over 13 M-tiles
    float tpart = 0.0f;
#pragma unroll 1
    for (int mt = 0; mt < 13; ++mt) {
        int mb = 16 * mt + 4 * q;       // this lane's 4 output rows
        f32x4 c2 = zero4;
        if (mb + 3 < 200) c2 = *(const f32x4*)(br2 + mb);
        int m2 = 16 * mt + n;           // A-row this lane loads
#pragma unroll
        for (int kk = 0; kk < 7; ++kk) {
            u32x4 af = {0u, 0u, 0u, 0u};
            if (m2 < 200) {
                int k0 = 32 * kk + 4 * q;
                const float* wr = Wr2 + m2 * 200 + k0;
                if (k0 + 3 < 200) {
                    float4 wa = *(const float4*)(wr);
                    af[0] = pkh(wa.x, wa.y); af[1] = pkh(wa.z, wa.w);
                }
                if (k0 + 19 < 200) {
                    float4 wb = *(const float4*)(wr + 16);
                    af[2] = pkh(wb.x, wb.y); af[3] = pkh(wb.z, wb.w);
                }
            }
            c2 = __builtin_amdgcn_mfma_f32_16x16x32_f16(
                __builtin_bit_cast(f16x8, af), hf2[kk], c2, 0, 0, 0);
        }
        float4 w3 = make_float4(0.f, 0.f, 0.f, 0.f);
        if (mb + 3 < 200) w3 = *(const float4*)(Wr3 + mb);
        tpart = fmaf(w3.x, gelu_exact(c2[0]), tpart);
        tpart = fmaf(w3.y, gelu_exact(c2[1]), tpart);
        tpart = fmaf(w3.z, gelu_exact(c2[2]), tpart);
        tpart = fmaf(w3.w, gelu_exact(c2[3]), tpart);
    }
    // reduce over the 4 q-groups (rows m mod 16 partition)
    tpart += __shfl_xor(tpart, 16);
    tpart += __shfl_xor(tpart, 32);

    // T10 -> E -> X_out (lane handles 8 columns p = 8q..8q+7)
    float tval = tpart + br3[0];
    float sig  = __fdividef(1.0f, 1.0f + __expf(-tval));
    float T10  = 0.1f + 6.9f * sig;
    float E    = __expf(-TRv[rowg] * __builtin_amdgcn_rcpf(T10));

    const float* Fr = Fin + rowg * 32 + 8 * q;
    float xo[8]; float ssum = 0.0f;
#pragma unroll
    for (int j = 0; j < 8; ++j) {
        float fa = Fr[j];
        float sn = __sinf(fa), cs = __cosf(fa);
        float v = __fdividef((1.0f - E) * sn, 1.0f - cs * E);
        xo[j] = v; ssum += v;
    }
    ssum += __shfl_xor(ssum, 16);
    ssum += __shfl_xor(ssum, 32);
    float mean2 = ssum / (float)fa_len[rowg];
    float inv   = __fdividef(1.0f, mean2);

    if (n < 8) {                        // cols 8..15 are duplicates: one writer
        float4* dst = (float4*)(out + rowg * 32 + 8 * q);
        dst[0] = make_float4(xo[0] * inv, xo[1] * inv, xo[2] * inv, xo[3] * inv);
        dst[1] = make_float4(xo[4] * inv, xo[5] * inv, xo[6] * inv, xo[7] * inv);
        if (q == 0) {
            out[B_ROWS * L_SEQ + rowg] = T10;
            out[B_ROWS * L_SEQ + B_ROWS + rowg] = 1.0f;
        }
    }
#undef XM
}

extern "C" void kernel_launch(void* const* d_in, const int* in_sizes, int n_in,
                              void* d_out, int out_size, void* d_ws, size_t ws_size,
                              hipStream_t stream) {
    const float* Xin  = (const float*)d_in[0];
    const float* Fin  = (const float*)d_in[1];
    const float* TRv  = (const float*)d_in[2];
    const float* Wi   = (const float*)d_in[3];
    const float* bi   = (const float*)d_in[4];
    const float* W1g  = (const float*)d_in[5];
    const float* b1g  = (const float*)d_in[6];
    const float* W2g  = (const float*)d_in[7];
    const float* b2g  = (const float*)d_in[8];
    const float* Wr1  = (const float*)d_in[9];
    const float* br1  = (const float*)d_in[10];
    const float* Wr2  = (const float*)d_in[11];
    const float* br2  = (const float*)d_in[12];
    const float* Wr3  = (const float*)d_in[13];
    const float* br3  = (const float*)d_in[14];
    const int*   flen = (const int*)d_in[16];

    float* outp = (float*)d_out;
    (void)d_ws; (void)ws_size;

    fused_kernel<<<dim3(B_ROWS / 32), dim3(256), 0, stream>>>(
        Xin, Fin, TRv, flen, Wi, bi, W1g, b1g, W2g, b2g,
        Wr1, br1, Wr2, br2, Wr3, br3, outp);
}

// Round 11
// 244.456 us; speedup vs baseline: 1.1442x; 1.1442x over previous
//
#include <hip/hip_runtime.h>
#include <hip/hip_bf16.h>

// Problem constants (fixed by the reference)
#define B_ROWS 16384
#define L_SEQ  32

typedef _Float16 f16;
typedef __attribute__((ext_vector_type(4))) _Float16 f16x4;
typedef __attribute__((ext_vector_type(8))) _Float16 f16x8;
typedef __attribute__((ext_vector_type(4))) float f32x4;
typedef __attribute__((ext_vector_type(4))) unsigned int u32x4;

// ---------- fast device math ----------
__device__ __forceinline__ unsigned pkh(float a, float b) {
    return __builtin_bit_cast(unsigned, __builtin_amdgcn_cvt_pkrtz(a, b));
}
__device__ __forceinline__ float tanh_fast(float x) {
    float e = __expf(2.0f * x);
    float r = __builtin_amdgcn_rcpf(e + 1.0f);
    return fmaf(-2.0f, r, 1.0f);
}
__device__ __forceinline__ float gelu_exact(float x) {
    return 0.5f * x * (1.0f + erff(x * 0.70710678118654752440f));
}
// opaque register pins: no remat/reload of weight fragments
__device__ __forceinline__ void pin2(uint2& v) {
    unsigned x0 = v.x, x1 = v.y;
    asm volatile("" : "+v"(x0), "+v"(x1));
    v = make_uint2(x0, x1);
}
__device__ __forceinline__ void pin4(u32x4& v) {
    unsigned x0 = v[0], x1 = v[1], x2 = v[2], x3 = v[3];
    asm volatile("" : "+v"(x0), "+v"(x1), "+v"(x2), "+v"(x3));
    v = (u32x4){x0, x1, x2, x3};
}

// ---------- Fused kernel: wave-PAIR cooperative RK4 ODE + readout ----------
// A pair of waves jointly owns 16 rows (all 16 MFMA columns REAL — no dup).
// Each wave: 8 layer-1 tiles + 4 layer-2 K-chunks (half the work); partial G
// exchanged via 2-phase LDS ping-pong, ONE barrier per FEVAL. tanh/k/z are
// recomputed bit-identically in both waves. Block = 4 waves = 2 pairs = 32
// rows; grid 512 -> 2 blocks/CU -> 2 waves/SIMD with zero duplicated MFMA.
__global__ __launch_bounds__(256, 2) void fused_kernel(
    const float* __restrict__ Xin, const float* __restrict__ Fin,
    const float* __restrict__ TRv,
    const int*   __restrict__ fa_len,
    const float* __restrict__ Wi,  const float* __restrict__ bi,
    const float* __restrict__ W1g, const float* __restrict__ b1g,
    const float* __restrict__ W2g, const float* __restrict__ b2g,
    const float* __restrict__ Wr1, const float* __restrict__ br1,
    const float* __restrict__ Wr2, const float* __restrict__ br2,
    const float* __restrict__ Wr3, const float* __restrict__ br3,
    float* __restrict__ out)
{
    __shared__ __align__(16) float xm[32 * 132];        // 16896 B
    __shared__ __align__(16) f32x4 exch[2][2][2][64];   // [pair][phase][half][lane] 8192 B
    __shared__ float texch[2][2][16];                   // readout scalar exchange
#define XM(r_, i_, c_) xm[(r_) * 132 + (i_) * 4 + (c_)]

    const int tid = threadIdx.x;
    const int g16 = tid >> 4, sub = tid & 15;

    // ---- Phase 1: preprocessing (push_zeros + fill), 2 rows per 16-lane group ----
    float mean_r[2]; int fl_r[2];
#pragma unroll
    for (int r = 0; r < 2; ++r) {
        const int row_l = g16 * 2 + r;
        const int row   = blockIdx.x * 32 + row_l;
        const float* Xr = Xin + row * L_SEQ;
        const float* Fr = Fin + row * L_SEQ;
        float xr0 = Xr[sub], xr1 = Xr[sub + 16];
        float fr0 = Fr[sub], fr1 = Fr[sub + 16];
        fl_r[r] = fa_len[row];
        float s = xr0 + xr1;
        s += __shfl_xor(s, 1, 16);
        s += __shfl_xor(s, 2, 16);
        s += __shfl_xor(s, 4, 16);
        s += __shfl_xor(s, 8, 16);
        mean_r[r] = s / (float)fl_r[r];
        XM(row_l, sub, 0)      = fr0; XM(row_l, sub, 1)      = xr0;
        XM(row_l, sub + 16, 0) = fr1; XM(row_l, sub + 16, 1) = xr1;
    }
    __syncthreads();

    float ff[2][2], xf[2][2];
#pragma unroll
    for (int r = 0; r < 2; ++r) {
        const int row_l = g16 * 2 + r;
        const int fl = fl_r[r];
        const float mean = mean_r[r];
        const int shift = L_SEQ - fl;
        int lsrc  = fl - 1 - shift;
        int lsrcC = lsrc < 0 ? 0 : lsrc;
        float lastX = (lsrc >= 0) ? (XM(row_l, lsrcC, 1) / mean) : 0.0f;
        float lastF = XM(row_l, fl - 1, 0);
#pragma unroll
        for (int u = 0; u < 2; ++u) {
            int p = sub + u * 16;
            int src = p - shift;
            int sc  = src < 0 ? 0 : src;
            float fraw = XM(row_l, sc, 0);
            float xraw = XM(row_l, sc, 1);
            ff[r][u] = (src >= 0) ? fraw : lastF;
            xf[r][u] = (src >= 0) ? (xraw / mean) : lastX;
        }
    }
    __syncthreads();
#pragma unroll
    for (int r = 0; r < 2; ++r) {
        const int row_l = g16 * 2 + r;
#pragma unroll
        for (int u = 0; u < 2; ++u) {
            int p = sub + u * 16;
            XM(row_l, p, 0) = ff[r][u];
            XM(row_l, p, 1) = xf[r][u];
        }
    }
    __syncthreads();
#pragma unroll
    for (int r = 0; r < 2; ++r) {
        const int row_l = g16 * 2 + r;
#pragma unroll
        for (int u = 0; u < 2; ++u) {
            int p = sub + u * 16;
            int qd = (p == 0) ? 1 : p;         // m[0] = x[1]-x[0]
            XM(row_l, p, 2) = XM(row_l, qd, 0) - XM(row_l, qd - 1, 0);
            XM(row_l, p, 3) = XM(row_l, qd, 1) - XM(row_l, qd - 1, 1);
        }
    }
    __syncthreads();

    // ---- MFMA-phase lane mapping ----
    const int wv   = tid >> 6;
    const int lane = tid & 63;
    const int pairId = wv >> 1;
    const int half   = wv & 1;
    const int n    = lane & 15;     // MFMA column = REAL row-in-pair
    const int q    = lane >> 4;     // lane quarter
    const int rowl = pairId * 16 + n;
    const int rowg = blockIdx.x * 32 + rowl;

    // Layer1 A = W1 (K=16 frag), this wave's 8 tiles: t = 8*half + tt.
    uint2 a1[8];
#pragma unroll
    for (int tt = 0; tt < 8; ++tt) {
        const int t = 8 * half + tt;
        const float* wr = W1g + (t * 16 + n) * 8 + (q < 2 ? q * 4 : 0);
        float4 w4 = *(const float4*)wr;
        float b1v = b1g[t * 16 + n];
        unsigned d0 = (q < 2) ? pkh(w4.x, w4.y) : (q == 2 ? pkh(b1v, 0.0f) : 0u);
        unsigned d1 = (q < 2) ? pkh(w4.z, w4.w) : 0u;
        a1[tt] = make_uint2(d0, d1);
        pin2(a1[tt]);
    }
    // Layer2 A = W2 [16 x 256], this wave's 4 K-chunks: kk = 4*half + tt.
    u32x4 a2[4];
#pragma unroll
    for (int tt = 0; tt < 4; ++tt) {
        const int kk = 4 * half + tt;
        const float* w2r = W2g + n * 256 + kk * 32 + 4 * q;
        float4 p0 = *(const float4*)(w2r);
        float4 p1 = *(const float4*)(w2r + 16);
        a2[tt] = (u32x4){pkh(p0.x, p0.y), pkh(p0.z, p0.w), pkh(p1.x, p1.y), pkh(p1.z, p1.w)};
        pin4(a2[tt]);
    }
    // b2 seed only in half 0 (else double-counted across the pair)
    f32x4 c2seed;
#pragma unroll
    for (int r = 0; r < 4; ++r) c2seed[r] = (half == 0) ? b2g[4 * q + r] : 0.0f;

    // z0 distributed: lane holds z[2q], z[2q+1] (f32 master) of row rowl
    float f0 = XM(rowl, 0, 0), X0 = XM(rowl, 0, 1);
    float z0 = fmaf(Wi[(2 * q) * 2], f0, fmaf(Wi[(2 * q) * 2 + 1], X0, bi[2 * q]));
    float z1 = fmaf(Wi[(2 * q + 1) * 2], f0, fmaf(Wi[(2 * q + 1) * 2 + 1], X0, bi[2 * q + 1]));

    // bpermute byte-index: lane (q,n) gathers z-pairs from lanes (q&1)*32+n (+16)
    const int bpi = (((q & 1) << 5) + n) << 2;
    const f32x4 zero4 = {0.f, 0.f, 0.f, 0.f};
    const f16x8 zf16 = {0, 0, 0, 0, 0, 0, 0, 0};

    auto make_bz = [&](float zza, float zzb) -> uint2 {
        unsigned myz = pkh(zza, zzb);
        int b0 = __builtin_amdgcn_ds_bpermute(bpi, (int)myz);
        int b1 = __builtin_amdgcn_ds_bpermute(bpi + 64, (int)myz);
        unsigned bz0 = (q < 2) ? (unsigned)b0 : (q == 2 ? 0x3C00u : 0u);
        unsigned bz1 = (q < 2) ? (unsigned)b1 : 0u;
        return make_uint2(bz0, bz1);
    };

    auto FEVAL = [&](int ph, float zza, float zzb, float d0c, float d1c,
                     float& ko0, float& ko1) {
        uint2 bzp = make_bz(zza, zzb);
        f16x4 bz = __builtin_bit_cast(f16x4, bzp);

        // layer 1 (this wave's half): 8 independent K=16 MFMAs
        f32x4 c1[8];
#pragma unroll
        for (int tt = 0; tt < 8; ++tt)
            c1[tt] = __builtin_amdgcn_mfma_f32_16x16x16f16(
                __builtin_bit_cast(f16x4, a1[tt]), bz, zero4, 0, 0, 0);

        // pack + packed relu: C-frag pair (2tt,2tt+1) IS layer-2 B-frag tt
        f16x8 hf[4];
#pragma unroll
        for (int tt = 0; tt < 4; ++tt) {
            u32x4 w = (u32x4){pkh(c1[2 * tt][0],     c1[2 * tt][1]),
                              pkh(c1[2 * tt][2],     c1[2 * tt][3]),
                              pkh(c1[2 * tt + 1][0], c1[2 * tt + 1][1]),
                              pkh(c1[2 * tt + 1][2], c1[2 * tt + 1][3])};
            hf[tt] = __builtin_elementwise_max(__builtin_bit_cast(f16x8, w), zf16);
        }

        // layer 2 (this wave's K-half): two 2-deep chains
        f32x4 c2a = c2seed, c2b = zero4;
        c2a = __builtin_amdgcn_mfma_f32_16x16x32_f16(
            __builtin_bit_cast(f16x8, a2[0]), hf[0], c2a, 0, 0, 0);
        c2b = __builtin_amdgcn_mfma_f32_16x16x32_f16(
            __builtin_bit_cast(f16x8, a2[2]), hf[2], c2b, 0, 0, 0);
        c2a = __builtin_amdgcn_mfma_f32_16x16x32_f16(
            __builtin_bit_cast(f16x8, a2[1]), hf[1], c2a, 0, 0, 0);
        c2b = __builtin_amdgcn_mfma_f32_16x16x32_f16(
            __builtin_bit_cast(f16x8, a2[3]), hf[3], c2b, 0, 0, 0);
        f32x4 Gp = c2a + c2b;

        // cross-wave exchange: 2-phase ping-pong, ONE barrier per FEVAL
        exch[pairId][ph][half][lane] = Gp;
        __syncthreads();
        f32x4 G = Gp + exch[pairId][ph][half ^ 1][lane];

        // g = tanh(G); lane holds G[4q..4q+3] -> k[2q], k[2q+1]
        float t0 = tanh_fast(G[0]), t1 = tanh_fast(G[1]);
        float t2 = tanh_fast(G[2]), t3 = tanh_fast(G[3]);
        ko0 = fmaf(t0, d0c, t1 * d1c);
        ko1 = fmaf(t2, d0c, t3 * d1c);
    };

    // ---- Phase 2: 31 intervals x 2 substeps of RK4 ----
    int ph = 0;
#pragma unroll 1
    for (int i = 0; i < 31; ++i) {
        float4 P0 = *(const float4*)&XM(rowl, i, 0);
        float4 P1 = *(const float4*)&XM(rowl, i + 1, 0);
        float m0f = P0.z, m0X = P0.w, m1f = P1.z, m1X = P1.w;
        float df  = P0.x - P1.x, dXx = P0.y - P1.y;

        float d25f = fmaf(-1.125f, df,  fmaf(0.1875f, m0f, -0.3125f * m1f));
        float d25X = fmaf(-1.125f, dXx, fmaf(0.1875f, m0X, -0.3125f * m1X));
        float d50f = fmaf(-1.5f,   df,  fmaf(-0.25f,  m0f, -0.25f   * m1f));
        float d50X = fmaf(-1.5f,   dXx, fmaf(-0.25f,  m0X, -0.25f   * m1X));
        float d75f = fmaf(-1.125f, df,  fmaf(-0.3125f, m0f, 0.1875f * m1f));
        float d75X = fmaf(-1.125f, dXx, fmaf(-0.3125f, m0X, 0.1875f * m1X));

#pragma unroll 1
        for (int ssi = 0; ssi < 2; ++ssi) {
            float daf = ssi ? d50f : m0f,  daX = ssi ? d50X : m0X;
            float dbf = ssi ? d75f : d25f, dbX = ssi ? d75X : d25X;
            float ddf = ssi ? m1f  : d50f, ddX = ssi ? m1X  : d50X;

            float k1a, k1b, k2a, k2b, k3a, k3b, k4a, k4b, zza, zzb;
            FEVAL(ph, z0, z1, daf, daX, k1a, k1b);       ph ^= 1;
            zza = fmaf(0.25f, k1a, z0); zzb = fmaf(0.25f, k1b, z1);
            FEVAL(ph, zza, zzb, dbf, dbX, k2a, k2b);     ph ^= 1;
            zza = fmaf(0.25f, k2a, z0); zzb = fmaf(0.25f, k2b, z1);
            FEVAL(ph, zza, zzb, dbf, dbX, k3a, k3b);     ph ^= 1;
            zza = fmaf(0.5f, k3a, z0);  zzb = fmaf(0.5f, k3b, z1);
            FEVAL(ph, zza, zzb, ddf, ddX, k4a, k4b);     ph ^= 1;

            float ka = fmaf(2.f, k2a, k1a); ka = fmaf(2.f, k3a, ka);
            float kb = fmaf(2.f, k2b, k1b); kb = fmaf(2.f, k3b, kb);
            z0 = fmaf(1.f / 12.f, ka + k4a, z0);
            z1 = fmaf(1.f / 12.f, kb + k4b, z1);
        }
    }

    // ---- Phase 3: readout ----
    // GEMM1 (full, both waves): h1 pre-activation, 13 M-tiles over Wr1
    uint2 bzp = make_bz(z0, z1);
    f16x4 bzr = __builtin_bit_cast(f16x4, bzp);
    f32x4 c1r[13];
#pragma unroll
    for (int t = 0; t < 13; ++t) {
        int m = 16 * t + n;
        uint2 afp = make_uint2(0u, 0u);
        if (q < 2) {
            if (m < 200) {
                float4 w4 = *(const float4*)(Wr1 + m * 8 + 4 * q);
                afp = make_uint2(pkh(w4.x, w4.y), pkh(w4.z, w4.w));
            }
        } else if (q == 2) {
            float b = (m < 200) ? br1[m] : 0.0f;
            afp.x = pkh(b, 0.0f);
        }
        c1r[t] = __builtin_amdgcn_mfma_f32_16x16x16f16(
            __builtin_bit_cast(f16x4, afp), bzr, zero4, 0, 0, 0);
    }

    // gelu + pack into B-frags for GEMM2 (C->B identity)
    f16x8 hf2[7];
#pragma unroll
    for (int kk = 0; kk < 7; ++kk) {
        float g0 = gelu_exact(c1r[2 * kk][0]), g1 = gelu_exact(c1r[2 * kk][1]);
        float g2 = gelu_exact(c1r[2 * kk][2]), g3 = gelu_exact(c1r[2 * kk][3]);
        float g4 = 0.f, g5 = 0.f, g6 = 0.f, g7 = 0.f;
        if (kk < 6) {
            g4 = gelu_exact(c1r[2 * kk + 1][0]); g5 = gelu_exact(c1r[2 * kk + 1][1]);
            g6 = gelu_exact(c1r[2 * kk + 1][2]); g7 = gelu_exact(c1r[2 * kk + 1][3]);
        }
        u32x4 w = (u32x4){pkh(g0, g1), pkh(g2, g3), pkh(g4, g5), pkh(g6, g7)};
        hf2[kk] = __builtin_bit_cast(f16x8, w);
    }

    // GEMM2: M-tiles split across the pair (half0: 0..6, half1: 7..12)
    float tpart = 0.0f;
    const int mt0 = half * 7, mt1 = half ? 13 : 7;
#pragma unroll 1
    for (int mt = mt0; mt < mt1; ++mt) {
        int mb = 16 * mt + 4 * q;
        f32x4 c2 = zero4;
        if (mb + 3 < 200) c2 = *(const f32x4*)(br2 + mb);
        int m2 = 16 * mt + n;
#pragma unroll
        for (int kk = 0; kk < 7; ++kk) {
            u32x4 af = {0u, 0u, 0u, 0u};
            if (m2 < 200) {
                int k0 = 32 * kk + 4 * q;
                const float* wr = Wr2 + m2 * 200 + k0;
                if (k0 + 3 < 200) {
                    float4 wa = *(const float4*)(wr);
                    af[0] = pkh(wa.x, wa.y); af[1] = pkh(wa.z, wa.w);
                }
                if (k0 + 19 < 200) {
                    float4 wb = *(const float4*)(wr + 16);
                    af[2] = pkh(wb.x, wb.y); af[3] = pkh(wb.z, wb.w);
                }
            }
            c2 = __builtin_amdgcn_mfma_f32_16x16x32_f16(
                __builtin_bit_cast(f16x8, af), hf2[kk], c2, 0, 0, 0);
        }
        float4 w3 = make_float4(0.f, 0.f, 0.f, 0.f);
        if (mb + 3 < 200) w3 = *(const float4*)(Wr3 + mb);
        tpart = fmaf(w3.x, gelu_exact(c2[0]), tpart);
        tpart = fmaf(w3.y, gelu_exact(c2[1]), tpart);
        tpart = fmaf(w3.z, gelu_exact(c2[2]), tpart);
        tpart = fmaf(w3.w, gelu_exact(c2[3]), tpart);
    }
    // reduce over q-groups, then across the pair
    tpart += __shfl_xor(tpart, 16);
    tpart += __shfl_xor(tpart, 32);
    if (lane < 16) texch[pairId][half][n] = tpart;
    __syncthreads();
    float tval = texch[pairId][0][n] + texch[pairId][1][n] + br3[0];

    // T10 -> E -> X_out (lane handles 8 columns p = 8q..8q+7)
    float sig  = __fdividef(1.0f, 1.0f + __expf(-tval));
    float T10  = 0.1f + 6.9f * sig;
    float E    = __expf(-TRv[rowg] * __builtin_amdgcn_rcpf(T10));

    const float* Fr = Fin + rowg * 32 + 8 * q;
    float xo[8]; float ssum = 0.0f;
#pragma unroll
    for (int j = 0; j < 8; ++j) {
        float fa = Fr[j];
        float sn = __sinf(fa), cs = __cosf(fa);
        float v = __fdividef((1.0f - E) * sn, 1.0f - cs * E);
        xo[j] = v; ssum += v;
    }
    ssum += __shfl_xor(ssum, 16);
    ssum += __shfl_xor(ssum, 32);
    float mean2 = ssum / (float)fa_len[rowg];
    float inv   = __fdividef(1.0f, mean2);

    if (half == 0) {                    // one writer per row
        float4* dst = (float4*)(out + rowg * 32 + 8 * q);
        dst[0] = make_float4(xo[0] * inv, xo[1] * inv, xo[2] * inv, xo[3] * inv);
        dst[1] = make_float4(xo[4] * inv, xo[5] * inv, xo[6] * inv, xo[7] * inv);
        if (q == 0) {
            out[B_ROWS * L_SEQ + rowg] = T10;
            out[B_ROWS * L_SEQ + B_ROWS + rowg] = 1.0f;
        }
    }
#undef XM
}

extern "C" void kernel_launch(void* const* d_in, const int* in_sizes, int n_in,
                              void* d_out, int out_size, void* d_ws, size_t ws_size,
                              hipStream_t stream) {
    const float* Xin  = (const float*)d_in[0];
    const float* Fin  = (const float*)d_in[1];
    const float* TRv  = (const float*)d_in[2];
    const float* Wi   = (const float*)d_in[3];
    const float* bi   = (const float*)d_in[4];
    const float* W1g  = (const float*)d_in[5];
    const float* b1g  = (const float*)d_in[6];
    const float* W2g  = (const float*)d_in[7];
    const float* b2g  = (const float*)d_in[8];
    const float* Wr1  = (const float*)d_in[9];
    const float* br1  = (const float*)d_in[10];
    const float* Wr2  = (const float*)d_in[11];
    const float* br2  = (const float*)d_in[12];
    const float* Wr3  = (const float*)d_in[13];
    const float* br3  = (const float*)d_in[14];
    const int*   flen = (const int*)d_in[16];

    float* outp = (float*)d_out;
    (void)d_ws; (void)ws_size;

    fused_kernel<<<dim3(B_ROWS / 32), dim3(256), 0, stream>>>(
        Xin, Fin, TRv, flen, Wi, bi, W1g, b1g, W2g, b2g,
        Wr1, br1, Wr2, br2, Wr3, br3, outp);
}